// Round 1
// baseline (300.622 us; speedup 1.0000x reference)
//
#include <hip/hip_runtime.h>
#include <cmath>

#define GAS __attribute__((address_space(1)))
#define LAS __attribute__((address_space(3)))

typedef __bf16 bf16x8 __attribute__((ext_vector_type(8)));
typedef float f32x4 __attribute__((ext_vector_type(4)));

__device__ __forceinline__ void gload16(const void* g, void* l) {
    __builtin_amdgcn_global_load_lds((const GAS void*)g, (LAS void*)l, 16, 0, 0);
}

// ---------------- fp32 -> bf16 strided convert (8 elems / thread) ----------------
__global__ void k_convert(const float* __restrict__ src, int src_ld,
                          __bf16* __restrict__ dst, int dst_ld,
                          int rows, int cols) {
    int idx = blockIdx.x * 256 + threadIdx.x;
    int c8 = cols >> 3;
    if (idx >= rows * c8) return;
    int r = idx / c8;
    int c = (idx - r * c8) << 3;
    const float4* s = reinterpret_cast<const float4*>(src + (long)r * src_ld + c);
    float4 x0 = s[0], x1 = s[1];
    bf16x8 v;
    v[0] = (__bf16)x0.x; v[1] = (__bf16)x0.y; v[2] = (__bf16)x0.z; v[3] = (__bf16)x0.w;
    v[4] = (__bf16)x1.x; v[5] = (__bf16)x1.y; v[6] = (__bf16)x1.z; v[7] = (__bf16)x1.w;
    *reinterpret_cast<bf16x8*>(dst + (long)r * dst_ld + c) = v;
}

// ---------------- fp32 [R][C] -> bf16 transpose [C][R] ----------------
__global__ void k_transpose(const float* __restrict__ src, int R, int C,
                            __bf16* __restrict__ dst) {
    __shared__ float t[32][33];
    int c0 = blockIdx.x * 32, r0 = blockIdx.y * 32;
    int tx = threadIdx.x, ty = threadIdx.y;  // 32 x 8
    #pragma unroll
    for (int i = 0; i < 32; i += 8)
        t[ty + i][tx] = src[(long)(r0 + ty + i) * C + c0 + tx];
    __syncthreads();
    #pragma unroll
    for (int i = 0; i < 32; i += 8)
        dst[(long)(c0 + ty + i) * R + r0 + tx] = (__bf16)t[tx][ty + i];
}

// ---------------- bias helpers ----------------
__global__ void k_bias_att(const float* __restrict__ Wo, const float* __restrict__ bv,
                           const float* __restrict__ bo, float* __restrict__ b_att) {
    int i = blockIdx.x;
    float s = 0.f;
    for (int k = threadIdx.x; k < 1024; k += 256) s += Wo[i * 1024 + k] * bv[k];
    __shared__ float red[256];
    red[threadIdx.x] = s;
    __syncthreads();
    for (int off = 128; off > 0; off >>= 1) {
        if (threadIdx.x < off) red[threadIdx.x] += red[threadIdx.x + off];
        __syncthreads();
    }
    if (threadIdx.x == 0) b_att[i] = red[0] + bo[i];
}

__global__ void k_bias_z2(const float* __restrict__ W1, const float* __restrict__ b_att,
                          const float* __restrict__ b1,
                          const __bf16* __restrict__ P, const __bf16* __restrict__ Q,
                          const float* __restrict__ bt, const float* __restrict__ bg,
                          const float* __restrict__ b2,
                          float* __restrict__ bz2, float* __restrict__ b_out) {
    int i = blockIdx.x;
    float s = 0.f;
    for (int k = threadIdx.x; k < 1024; k += 256) {
        s += (W1[(long)i * 2048 + k] + W1[(long)i * 2048 + 1024 + k]) * b_att[k];
        s += (float)P[i * 1024 + k] * bt[k];
        s += (float)Q[i * 1024 + k] * bg[k];
    }
    __shared__ float red[256];
    red[threadIdx.x] = s;
    __syncthreads();
    for (int off = 128; off > 0; off >>= 1) {
        if (threadIdx.x < off) red[threadIdx.x] += red[threadIdx.x + off];
        __syncthreads();
    }
    if (threadIdx.x == 0) {
        bz2[i] = red[0] + b1[i];
        b_out[i] = b2[i] + bg[i] + bt[i];
    }
}

// ---------------- NT GEMM: C[M,N] = A[M,K] * B[N,K]^T  (bf16 in, fp32 acc) ------
// MODE 0: store bf16 (no bias); MODE 1: +bias, exact GELU, store bf16; MODE 2: +bias, store fp32
template <int BM, int BN, int MODE>
__global__ __launch_bounds__(256, 2) void k_gemm_nt(
    const __bf16* __restrict__ A, int lda,
    const __bf16* __restrict__ B, int ldb,
    void* __restrict__ Cv, int ldc,
    const float* __restrict__ bias,
    int K, int n_tiles) {
    constexpr int BK = 32;
    constexpr int MR = BM / 32, NR = BN / 32;  // per-wave 16x16 frags (2x2 wave grid)
    __shared__ alignas(16) __bf16 As[2][BM][BK];
    __shared__ alignas(16) __bf16 Bs[2][BN][BK];

    const int tid = threadIdx.x;
    const int lane = tid & 63;
    const int wave = tid >> 6;
    const int bid = blockIdx.x;
    const int bn = bid % n_tiles;
    const int bm = bid / n_tiles;
    const int m0 = bm * BM, n0 = bn * BN;

    // staging map: flat byte f = it*4096 + wave*1024 + lane*16  (matches lds base+lane*16)
    const int srow = tid >> 2;            // 64B rows
    const int scol = (tid & 3) << 3;      // bf16 elems

    const __bf16* Ab = A + (long)(m0 + srow) * lda + scol;
    const __bf16* Bb = B + (long)(n0 + srow) * ldb + scol;

    const int wr = (wave >> 1) * (BM / 2);
    const int wc = (wave & 1) * (BN / 2);
    const int fr = lane & 15;
    const int kq = (lane >> 4) << 3;

    f32x4 acc[MR][NR] = {};

    const int nk = K / BK;

    auto stage = [&](int buf, int kt) {
        #pragma unroll
        for (int it = 0; it < BM / 64; ++it)
            gload16(Ab + (long)(it * 64) * lda + kt * BK, &As[buf][srow + it * 64][scol]);
        #pragma unroll
        for (int it = 0; it < BN / 64; ++it)
            gload16(Bb + (long)(it * 64) * ldb + kt * BK, &Bs[buf][srow + it * 64][scol]);
    };

    stage(0, 0);
    for (int kt = 0; kt < nk; ++kt) {
        const int buf = kt & 1;
        __syncthreads();               // drains vmcnt -> buf ready; prev compute done
        if (kt + 1 < nk) stage(buf ^ 1, kt + 1);
        bf16x8 af[MR], bfr[NR];
        #pragma unroll
        for (int m = 0; m < MR; ++m)
            af[m] = *(const bf16x8*)(&As[buf][wr + m * 16 + fr][kq]);
        #pragma unroll
        for (int n = 0; n < NR; ++n)
            bfr[n] = *(const bf16x8*)(&Bs[buf][wc + n * 16 + fr][kq]);
        #pragma unroll
        for (int m = 0; m < MR; ++m)
            #pragma unroll
            for (int n = 0; n < NR; ++n)
                acc[m][n] = __builtin_amdgcn_mfma_f32_16x16x32_bf16(af[m], bfr[n], acc[m][n], 0, 0, 0);
    }

    // epilogue: D row = (lane>>4)*4 + r, col = lane&15 (m89-verified layout)
    const int r0 = (lane >> 4) << 2;
    #pragma unroll
    for (int n = 0; n < NR; ++n) {
        const int gc = n0 + wc + n * 16 + fr;
        const float bval = (MODE != 0 && bias) ? bias[gc] : 0.0f;
        #pragma unroll
        for (int m = 0; m < MR; ++m) {
            const long rbase = (long)(m0 + wr + m * 16 + r0);
            #pragma unroll
            for (int r = 0; r < 4; ++r) {
                float v = acc[m][n][r] + bval;
                const long row = rbase + r;
                if (MODE == 0) {
                    ((__bf16*)Cv)[row * ldc + gc] = (__bf16)v;
                } else if (MODE == 1) {
                    v = 0.5f * v * (1.0f + erff(v * 0.70710678118f));
                    ((__bf16*)Cv)[row * ldc + gc] = (__bf16)v;
                } else {
                    ((float*)Cv)[row * ldc + gc] = v;
                }
            }
        }
    }
}

// ---------------- host ----------------
extern "C" void kernel_launch(void* const* d_in, const int* in_sizes, int n_in,
                              void* d_out, int out_size, void* d_ws, size_t ws_size,
                              hipStream_t stream) {
    constexpr int Bsz = 16384, F = 1024, GD = 512, TD = 768;
    constexpr int XLD = F + GD + TD;  // 2304

    const float* gnn = (const float*)d_in[0];
    const float* tr  = (const float*)d_in[1];
    const float* Wg  = (const float*)d_in[2];
    const float* bg  = (const float*)d_in[3];
    const float* Wt  = (const float*)d_in[4];
    const float* bt  = (const float*)d_in[5];
    const float* Wv  = (const float*)d_in[6];
    const float* bv  = (const float*)d_in[7];
    const float* Wo  = (const float*)d_in[8];
    const float* bo  = (const float*)d_in[9];
    const float* W1  = (const float*)d_in[10];
    const float* b1  = (const float*)d_in[11];
    const float* W2  = (const float*)d_in[12];
    const float* b2  = (const float*)d_in[13];
    float* out = (float*)d_out;

    char* w = (char*)d_ws;
    auto alloc = [&](size_t bytes) {
        char* p = w;
        w += (bytes + 255) & ~(size_t)255;
        return p;
    };
    __bf16* X    = (__bf16*)alloc((size_t)Bsz * XLD * 2);       // [h | gnn | tr]
    __bf16* M1   = (__bf16*)alloc((size_t)F * (GD + TD) * 2);   // [Mg | Mt]
    __bf16* Wp   = (__bf16*)alloc((size_t)F * XLD * 2);         // [W2 | Wg | Wt]
    __bf16* WvT  = (__bf16*)alloc((size_t)F * F * 2);
    __bf16* WgT  = (__bf16*)alloc((size_t)GD * F * 2);
    __bf16* WtT  = (__bf16*)alloc((size_t)TD * F * 2);
    __bf16* Wo_b = (__bf16*)alloc((size_t)F * F * 2);
    __bf16* W1a  = (__bf16*)alloc((size_t)F * F * 2);
    __bf16* W1b  = (__bf16*)alloc((size_t)F * F * 2);
    __bf16* AT   = (__bf16*)alloc((size_t)F * F * 2);
    __bf16* P    = (__bf16*)alloc((size_t)F * F * 2);
    __bf16* Q    = (__bf16*)alloc((size_t)F * F * 2);
    float* b_att = (float*)alloc(F * 4);
    float* bz2   = (float*)alloc(F * 4);
    float* b_out = (float*)alloc(F * 4);
    if ((size_t)(w - (char*)d_ws) > ws_size) return;  // workspace too small (shouldn't happen)

    dim3 b256(256);
    auto cgrid = [](long rows, long cols) { return dim3((unsigned)((rows * (cols >> 3) + 255) / 256)); };

    // --- converts ---
    k_convert<<<cgrid(Bsz, GD), b256, 0, stream>>>(gnn, GD, X + F, XLD, Bsz, GD);
    k_convert<<<cgrid(Bsz, TD), b256, 0, stream>>>(tr, TD, X + F + GD, XLD, Bsz, TD);
    k_convert<<<cgrid(F, F), b256, 0, stream>>>(Wo, F, Wo_b, F, F, F);
    k_convert<<<cgrid(F, F), b256, 0, stream>>>(W1, 2 * F, W1a, F, F, F);
    k_convert<<<cgrid(F, F), b256, 0, stream>>>(W1 + F, 2 * F, W1b, F, F, F);
    k_convert<<<cgrid(F, F), b256, 0, stream>>>(W2, F, Wp, XLD, F, F);
    k_convert<<<cgrid(F, GD), b256, 0, stream>>>(Wg, GD, Wp + F, XLD, F, GD);
    k_convert<<<cgrid(F, TD), b256, 0, stream>>>(Wt, TD, Wp + F + GD, XLD, F, TD);

    // --- transposes (fp32 src -> bf16 dst) ---
    dim3 tb(32, 8);
    k_transpose<<<dim3(F / 32, F / 32), tb, 0, stream>>>(Wv, F, F, WvT);
    k_transpose<<<dim3(GD / 32, F / 32), tb, 0, stream>>>(Wg, F, GD, WgT);
    k_transpose<<<dim3(TD / 32, F / 32), tb, 0, stream>>>(Wt, F, TD, WtT);

    // --- bias chain part 1 ---
    k_bias_att<<<dim3(F), b256, 0, stream>>>(Wo, bv, bo, b_att);

    // --- weight-composition GEMMs (64x64 tiles) ---
    // AT = (Wo@Wv)^T = NT(WvT, Wo)
    k_gemm_nt<64, 64, 0><<<dim3((F / 64) * (F / 64)), b256, 0, stream>>>(
        WvT, F, Wo_b, F, AT, F, nullptr, F, F / 64);
    // P = W1a@A = NT(W1a, AT) ; Q = W1b@A
    k_gemm_nt<64, 64, 0><<<dim3((F / 64) * (F / 64)), b256, 0, stream>>>(
        W1a, F, AT, F, P, F, nullptr, F, F / 64);
    k_gemm_nt<64, 64, 0><<<dim3((F / 64) * (F / 64)), b256, 0, stream>>>(
        W1b, F, AT, F, Q, F, nullptr, F, F / 64);
    // Mg = Q@Wg = NT(Q, WgT) -> M1[:, 0:512]
    k_gemm_nt<64, 64, 0><<<dim3((F / 64) * (GD / 64)), b256, 0, stream>>>(
        Q, F, WgT, F, M1, GD + TD, nullptr, F, GD / 64);
    // Mt = P@Wt = NT(P, WtT) -> M1[:, 512:1280]
    k_gemm_nt<64, 64, 0><<<dim3((F / 64) * (TD / 64)), b256, 0, stream>>>(
        P, F, WtT, F, M1 + GD, GD + TD, nullptr, F, TD / 64);

    // --- bias chain part 2 ---
    k_bias_z2<<<dim3(F), b256, 0, stream>>>(W1, b_att, b1, P, Q, bt, bg, b2, bz2, b_out);

    // --- pass 1: h = gelu([gnn|tr] @ M1^T + bz2) -> X[:, 0:1024] (bf16) ---
    k_gemm_nt<128, 128, 1><<<dim3((Bsz / 128) * (F / 128)), b256, 0, stream>>>(
        X + F, XLD, M1, GD + TD, X, XLD, bz2, GD + TD, F / 128);

    // --- pass 2: out = [h|gnn|tr] @ [W2|Wg|Wt]^T + b_out (fp32) ---
    k_gemm_nt<128, 128, 2><<<dim3((Bsz / 128) * (F / 128)), b256, 0, stream>>>(
        X, XLD, Wp, XLD, out, F, b_out, XLD, F / 128);
}

// Round 2
// 246.803 us; speedup vs baseline: 1.2181x; 1.2181x over previous
//
#include <hip/hip_runtime.h>
#include <cmath>

#define GAS __attribute__((address_space(1)))
#define LAS __attribute__((address_space(3)))

typedef __bf16 bf16x8 __attribute__((ext_vector_type(8)));
typedef float f32x4 __attribute__((ext_vector_type(4)));

__device__ __forceinline__ void gload16(const void* g, void* l) {
    __builtin_amdgcn_global_load_lds((const GAS void*)g, (LAS void*)l, 16, 0, 0);
}

// ---------------- merged fp32 -> bf16 converts (8 elems / thread) ----------------
// segments: gnn->X[:,1024:1536], tr->X[:,1536:2304], Wo->Wo_b, W1a/W1b->W1ab,
//           W2->Wp[:,0:1024], Wg->Wp[:,1024:1536], Wt->Wp[:,1536:2304]
__global__ void k_prep_convert(const float* __restrict__ gnn, const float* __restrict__ tr,
                               const float* __restrict__ Wo, const float* __restrict__ W1,
                               const float* __restrict__ W2, const float* __restrict__ Wg,
                               const float* __restrict__ Wt,
                               __bf16* __restrict__ X, __bf16* __restrict__ Wo_b,
                               __bf16* __restrict__ W1ab, __bf16* __restrict__ Wp) {
    int b = blockIdx.x;
    const float* src; __bf16* dst; int sld, dld, base, c8;
    if (b < 4096)       { src = gnn;       sld = 512;  dst = X + 1024;        dld = 2304; base = 0;     c8 = 64; }
    else if (b < 10240) { src = tr;        sld = 768;  dst = X + 1536;        dld = 2304; base = 4096;  c8 = 96; }
    else if (b < 10752) { src = Wo;        sld = 1024; dst = Wo_b;            dld = 1024; base = 10240; c8 = 128; }
    else if (b < 11264) { src = W1;        sld = 2048; dst = W1ab;            dld = 1024; base = 10752; c8 = 128; }
    else if (b < 11776) { src = W1 + 1024; sld = 2048; dst = W1ab + 1024*1024; dld = 1024; base = 11264; c8 = 128; }
    else if (b < 12288) { src = W2;        sld = 1024; dst = Wp;              dld = 2304; base = 11776; c8 = 128; }
    else if (b < 12544) { src = Wg;        sld = 512;  dst = Wp + 1024;       dld = 2304; base = 12288; c8 = 64; }
    else                { src = Wt;        sld = 768;  dst = Wp + 1536;       dld = 2304; base = 12544; c8 = 96; }
    int idx = (b - base) * 256 + threadIdx.x;
    int r = idx / c8;
    int c = (idx - r * c8) << 3;
    const float4* s = reinterpret_cast<const float4*>(src + (long)r * sld + c);
    float4 x0 = s[0], x1 = s[1];
    bf16x8 v;
    v[0] = (__bf16)x0.x; v[1] = (__bf16)x0.y; v[2] = (__bf16)x0.z; v[3] = (__bf16)x0.w;
    v[4] = (__bf16)x1.x; v[5] = (__bf16)x1.y; v[6] = (__bf16)x1.z; v[7] = (__bf16)x1.w;
    *reinterpret_cast<bf16x8*>(dst + (long)r * dld + c) = v;
}

// ---------------- merged fp32 [R][C] -> bf16 [C][R] transposes ----------------
__global__ void k_prep_transpose(const float* __restrict__ Wv, const float* __restrict__ Wg,
                                 const float* __restrict__ Wt,
                                 __bf16* __restrict__ WvT, __bf16* __restrict__ WgT,
                                 __bf16* __restrict__ WtT) {
    __shared__ float t[32][33];
    int b = blockIdx.x;
    const float* src; __bf16* dst; int R, C, tile;
    if (b < 1024)      { src = Wv; dst = WvT; R = 1024; C = 1024; tile = b; }
    else if (b < 1536) { src = Wg; dst = WgT; R = 1024; C = 512;  tile = b - 1024; }
    else               { src = Wt; dst = WtT; R = 1024; C = 768;  tile = b - 1536; }
    int tx_n = C >> 5;
    int c0 = (tile % tx_n) << 5, r0 = (tile / tx_n) << 5;
    int tx = threadIdx.x, ty = threadIdx.y;  // 32 x 8
    #pragma unroll
    for (int i = 0; i < 32; i += 8)
        t[ty + i][tx] = src[(long)(r0 + ty + i) * C + c0 + tx];
    __syncthreads();
    #pragma unroll
    for (int i = 0; i < 32; i += 8)
        dst[(long)(c0 + ty + i) * R + r0 + tx] = (__bf16)t[tx][ty + i];
}

// ---------------- bias helpers ----------------
__global__ void k_bias_att(const float* __restrict__ Wo, const float* __restrict__ bv,
                           const float* __restrict__ bo, float* __restrict__ b_att) {
    int i = blockIdx.x;
    float s = 0.f;
    for (int k = threadIdx.x; k < 1024; k += 256) s += Wo[i * 1024 + k] * bv[k];
    __shared__ float red[256];
    red[threadIdx.x] = s;
    __syncthreads();
    for (int off = 128; off > 0; off >>= 1) {
        if (threadIdx.x < off) red[threadIdx.x] += red[threadIdx.x + off];
        __syncthreads();
    }
    if (threadIdx.x == 0) b_att[i] = red[0] + bo[i];
}

__global__ void k_bias_z2(const float* __restrict__ W1, const float* __restrict__ b_att,
                          const float* __restrict__ b1,
                          const __bf16* __restrict__ P, const __bf16* __restrict__ Q,
                          const float* __restrict__ bt, const float* __restrict__ bg,
                          const float* __restrict__ b2,
                          float* __restrict__ bz2, float* __restrict__ b_out) {
    int i = blockIdx.x;
    float s = 0.f;
    for (int k = threadIdx.x; k < 1024; k += 256) {
        s += (W1[(long)i * 2048 + k] + W1[(long)i * 2048 + 1024 + k]) * b_att[k];
        s += (float)P[i * 1024 + k] * bt[k];
        s += (float)Q[i * 1024 + k] * bg[k];
    }
    __shared__ float red[256];
    red[threadIdx.x] = s;
    __syncthreads();
    for (int off = 128; off > 0; off >>= 1) {
        if (threadIdx.x < off) red[threadIdx.x] += red[threadIdx.x + off];
        __syncthreads();
    }
    if (threadIdx.x == 0) {
        bz2[i] = red[0] + b1[i];
        b_out[i] = b2[i] + bg[i] + bt[i];
    }
}

// ---------------- NT GEMM: C[M,N] = A[M,K] * B[N,K]^T  (bf16 in, fp32 acc) ------
// LDS layout XOR-swizzled: phys_byte = (r*64 + b) ^ ((r&7)<<4)  (64B rows, BK=32)
// Applied on BOTH sides: pre-swizzled global source for global_load_lds (linear
// LDS dest) + swizzled ds_read address (rule #21 both-sides-or-neither).
// MODE 0: store bf16; MODE 1: +bias, exact GELU, store bf16; MODE 2: +bias, fp32
template <int BM, int BN, int MODE>
__global__ __launch_bounds__(256, 2) void k_gemm_nt(
    const __bf16* __restrict__ A, int lda,
    const __bf16* __restrict__ B, int ldb,
    void* __restrict__ Cv, int ldc,
    const float* __restrict__ bias,
    int K, int n_tiles) {
    constexpr int BK = 32;
    constexpr int MR = BM / 32, NR = BN / 32;  // per-wave 16x16 frags (2x2 wave grid)
    __shared__ alignas(16) __bf16 As[2][BM][BK];
    __shared__ alignas(16) __bf16 Bs[2][BN][BK];

    const int tid = threadIdx.x;
    const int lane = tid & 63;
    const int wave = tid >> 6;

    // XCD-aware bijective block swizzle (all grids here are multiples of 8):
    // each XCD gets a contiguous chunk of bm-major tile space -> A stripe +
    // full B fit the XCD's cache path instead of every XCD streaming all of A.
    int bid = blockIdx.x;
    const int nwg = gridDim.x;
    if ((nwg & 7) == 0) bid = (bid & 7) * (nwg >> 3) + (bid >> 3);
    const int bn = bid % n_tiles;
    const int bm = bid / n_tiles;
    const int m0 = bm * BM, n0 = bn * BN;

    // staging: this thread fills physical LDS bytes it*4096 + tid*16
    const int rp_l = tid >> 2;        // physical row within 64-row chunk
    const int sp = tid & 3;           // physical 16B slot

    const int wr = (wave >> 1) * (BM / 2);
    const int wc = (wave & 1) * (BN / 2);
    const int fr = lane & 15;
    const int fb = (lane >> 4) << 4;  // fragment byte offset in 64B row

    f32x4 acc[MR][NR] = {};
    const int nk = K / BK;

    auto stage = [&](int buf, int kt) {
        char* abase = (char*)&As[buf][0][0];
        char* bbase = (char*)&Bs[buf][0][0];
        #pragma unroll
        for (int it = 0; it < BM / 64; ++it) {
            int rp = it * 64 + rp_l;
            int rl = (rp & ~1) | ((rp ^ (rp >> 2)) & 1);  // inverse row swizzle
            int sl = sp ^ (rl & 3);                        // inverse slot swizzle
            gload16(A + (long)(m0 + rl) * lda + kt * BK + sl * 8,
                    abase + it * 4096 + tid * 16);
        }
        #pragma unroll
        for (int it = 0; it < BN / 64; ++it) {
            int rp = it * 64 + rp_l;
            int rl = (rp & ~1) | ((rp ^ (rp >> 2)) & 1);
            int sl = sp ^ (rl & 3);
            gload16(B + (long)(n0 + rl) * ldb + kt * BK + sl * 8,
                    bbase + it * 4096 + tid * 16);
        }
    };

    stage(0, 0);
    for (int kt = 0; kt < nk; ++kt) {
        const int buf = kt & 1;
        __syncthreads();               // drains vmcnt -> buf ready; prev compute done
        if (kt + 1 < nk) stage(buf ^ 1, kt + 1);
        const char* abase = (const char*)&As[buf][0][0];
        const char* bbase = (const char*)&Bs[buf][0][0];
        bf16x8 af[MR], bfr[NR];
        #pragma unroll
        for (int m = 0; m < MR; ++m) {
            int r = wr + m * 16 + fr;
            af[m] = *(const bf16x8*)(abase + (((r << 6) + fb) ^ ((r & 7) << 4)));
        }
        #pragma unroll
        for (int n = 0; n < NR; ++n) {
            int r = wc + n * 16 + fr;
            bfr[n] = *(const bf16x8*)(bbase + (((r << 6) + fb) ^ ((r & 7) << 4)));
        }
        #pragma unroll
        for (int m = 0; m < MR; ++m)
            #pragma unroll
            for (int n = 0; n < NR; ++n)
                acc[m][n] = __builtin_amdgcn_mfma_f32_16x16x32_bf16(af[m], bfr[n], acc[m][n], 0, 0, 0);
    }

    // epilogue: D row = (lane>>4)*4 + r, col = lane&15 (m89-verified layout)
    const int r0 = (lane >> 4) << 2;
    #pragma unroll
    for (int n = 0; n < NR; ++n) {
        const int gc = n0 + wc + n * 16 + fr;
        const float bval = (MODE != 0 && bias) ? bias[gc] : 0.0f;
        #pragma unroll
        for (int m = 0; m < MR; ++m) {
            const long rbase = (long)(m0 + wr + m * 16 + r0);
            #pragma unroll
            for (int r = 0; r < 4; ++r) {
                float v = acc[m][n][r] + bval;
                const long row = rbase + r;
                if (MODE == 0) {
                    ((__bf16*)Cv)[row * ldc + gc] = (__bf16)v;
                } else if (MODE == 1) {
                    v = 0.5f * v * (1.0f + erff(v * 0.70710678118f));
                    ((__bf16*)Cv)[row * ldc + gc] = (__bf16)v;
                } else {
                    ((float*)Cv)[row * ldc + gc] = v;
                }
            }
        }
    }
}

// ---------------- host ----------------
extern "C" void kernel_launch(void* const* d_in, const int* in_sizes, int n_in,
                              void* d_out, int out_size, void* d_ws, size_t ws_size,
                              hipStream_t stream) {
    constexpr int Bsz = 16384, F = 1024, GD = 512, TD = 768;
    constexpr int XLD = F + GD + TD;  // 2304

    const float* gnn = (const float*)d_in[0];
    const float* tr  = (const float*)d_in[1];
    const float* Wg  = (const float*)d_in[2];
    const float* bg  = (const float*)d_in[3];
    const float* Wt  = (const float*)d_in[4];
    const float* bt  = (const float*)d_in[5];
    const float* Wv  = (const float*)d_in[6];
    const float* bv  = (const float*)d_in[7];
    const float* Wo  = (const float*)d_in[8];
    const float* bo  = (const float*)d_in[9];
    const float* W1  = (const float*)d_in[10];
    const float* b1  = (const float*)d_in[11];
    const float* W2  = (const float*)d_in[12];
    const float* b2  = (const float*)d_in[13];
    float* out = (float*)d_out;

    char* w = (char*)d_ws;
    auto alloc = [&](size_t bytes) {
        char* p = w;
        w += (bytes + 255) & ~(size_t)255;
        return p;
    };
    __bf16* X    = (__bf16*)alloc((size_t)Bsz * XLD * 2);       // [h | gnn | tr]
    __bf16* M1   = (__bf16*)alloc((size_t)F * (GD + TD) * 2);   // [Mg | Mt]
    __bf16* Wp   = (__bf16*)alloc((size_t)F * XLD * 2);         // [W2 | Wg | Wt]
    __bf16* WvT  = (__bf16*)alloc((size_t)F * F * 2);
    __bf16* WgT  = (__bf16*)alloc((size_t)GD * F * 2);
    __bf16* WtT  = (__bf16*)alloc((size_t)TD * F * 2);
    __bf16* Wo_b = (__bf16*)alloc((size_t)F * F * 2);
    __bf16* W1ab = (__bf16*)alloc((size_t)2 * F * F * 2);       // [W1a ; W1b]
    __bf16* AT   = (__bf16*)alloc((size_t)F * F * 2);
    __bf16* PQ   = (__bf16*)alloc((size_t)2 * F * F * 2);       // [P ; Q]
    float* b_att = (float*)alloc(F * 4);
    float* bz2   = (float*)alloc(F * 4);
    float* b_out = (float*)alloc(F * 4);
    if ((size_t)(w - (char*)d_ws) > ws_size) return;

    dim3 b256(256);
    __bf16* P = PQ;
    __bf16* Q = PQ + (size_t)F * F;

    // --- all fp32->bf16 converts in one launch (12928 blocks) ---
    k_prep_convert<<<dim3(12928), b256, 0, stream>>>(gnn, tr, Wo, W1, W2, Wg, Wt,
                                                     X, Wo_b, W1ab, Wp);
    // --- all transposes in one launch (2304 blocks) ---
    k_prep_transpose<<<dim3(2304), dim3(32, 8), 0, stream>>>(Wv, Wg, Wt, WvT, WgT, WtT);

    // --- bias chain part 1 ---
    k_bias_att<<<dim3(F), b256, 0, stream>>>(Wo, bv, bo, b_att);

    // --- weight-composition GEMMs (64x64 tiles) ---
    // AT = (Wo@Wv)^T = NT(WvT, Wo)
    k_gemm_nt<64, 64, 0><<<dim3((F / 64) * (F / 64)), b256, 0, stream>>>(
        WvT, F, Wo_b, F, AT, F, nullptr, F, F / 64);
    // [P;Q] = [W1a;W1b]@A = NT(W1ab, AT), M=2048
    k_gemm_nt<64, 64, 0><<<dim3((2 * F / 64) * (F / 64)), b256, 0, stream>>>(
        W1ab, F, AT, F, PQ, F, nullptr, F, F / 64);
    // Mg = Q@Wg = NT(Q, WgT) -> M1[:, 0:512]
    k_gemm_nt<64, 64, 0><<<dim3((F / 64) * (GD / 64)), b256, 0, stream>>>(
        Q, F, WgT, F, M1, GD + TD, nullptr, F, GD / 64);
    // Mt = P@Wt = NT(P, WtT) -> M1[:, 512:1280]
    k_gemm_nt<64, 64, 0><<<dim3((F / 64) * (TD / 64)), b256, 0, stream>>>(
        P, F, WtT, F, M1 + GD, GD + TD, nullptr, F, TD / 64);

    // --- bias chain part 2 ---
    k_bias_z2<<<dim3(F), b256, 0, stream>>>(W1, b_att, b1, P, Q, bt, bg, b2, bz2, b_out);

    // --- pass 1: h = gelu([gnn|tr] @ M1^T + bz2) -> X[:, 0:1024] (bf16) ---
    k_gemm_nt<128, 128, 1><<<dim3((Bsz / 128) * (F / 128)), b256, 0, stream>>>(
        X + F, XLD, M1, GD + TD, X, XLD, bz2, GD + TD, F / 128);

    // --- pass 2: out = [h|gnn|tr] @ [W2|Wg|Wt]^T + b_out (fp32) ---
    k_gemm_nt<128, 128, 2><<<dim3((Bsz / 128) * (F / 128)), b256, 0, stream>>>(
        X, XLD, Wp, XLD, out, F, b_out, XLD, F / 128);
}

// Round 3
// 225.556 us; speedup vs baseline: 1.3328x; 1.0942x over previous
//
#include <hip/hip_runtime.h>
#include <cmath>

#define GAS __attribute__((address_space(1)))
#define LAS __attribute__((address_space(3)))

typedef __bf16 bf16x8 __attribute__((ext_vector_type(8)));
typedef float f32x4 __attribute__((ext_vector_type(4)));

__device__ __forceinline__ void gload16(const void* g, void* l) {
    __builtin_amdgcn_global_load_lds((const GAS void*)g, (LAS void*)l, 16, 0, 0);
}

// ---------------- merged fp32 -> bf16 converts (8 elems / thread) ----------------
__global__ void k_prep_convert(const float* __restrict__ gnn, const float* __restrict__ tr,
                               const float* __restrict__ Wo, const float* __restrict__ W1,
                               const float* __restrict__ W2, const float* __restrict__ Wg,
                               const float* __restrict__ Wt,
                               __bf16* __restrict__ X, __bf16* __restrict__ Wo_b,
                               __bf16* __restrict__ W1ab, __bf16* __restrict__ Wp) {
    int b = blockIdx.x;
    const float* src; __bf16* dst; int sld, dld, base, c8;
    if (b < 4096)       { src = gnn;       sld = 512;  dst = X + 1024;        dld = 2304; base = 0;     c8 = 64; }
    else if (b < 10240) { src = tr;        sld = 768;  dst = X + 1536;        dld = 2304; base = 4096;  c8 = 96; }
    else if (b < 10752) { src = Wo;        sld = 1024; dst = Wo_b;            dld = 1024; base = 10240; c8 = 128; }
    else if (b < 11264) { src = W1;        sld = 2048; dst = W1ab;            dld = 1024; base = 10752; c8 = 128; }
    else if (b < 11776) { src = W1 + 1024; sld = 2048; dst = W1ab + 1024*1024; dld = 1024; base = 11264; c8 = 128; }
    else if (b < 12288) { src = W2;        sld = 1024; dst = Wp;              dld = 2304; base = 11776; c8 = 128; }
    else if (b < 12544) { src = Wg;        sld = 512;  dst = Wp + 1024;       dld = 2304; base = 12288; c8 = 64; }
    else                { src = Wt;        sld = 768;  dst = Wp + 1536;       dld = 2304; base = 12544; c8 = 96; }
    int idx = (b - base) * 256 + threadIdx.x;
    int r = idx / c8;
    int c = (idx - r * c8) << 3;
    const float4* s = reinterpret_cast<const float4*>(src + (long)r * sld + c);
    float4 x0 = s[0], x1 = s[1];
    bf16x8 v;
    v[0] = (__bf16)x0.x; v[1] = (__bf16)x0.y; v[2] = (__bf16)x0.z; v[3] = (__bf16)x0.w;
    v[4] = (__bf16)x1.x; v[5] = (__bf16)x1.y; v[6] = (__bf16)x1.z; v[7] = (__bf16)x1.w;
    *reinterpret_cast<bf16x8*>(dst + (long)r * dld + c) = v;
}

// ---------------- merged fp32 [R][C] -> bf16 [C][R] transposes ----------------
__global__ void k_prep_transpose(const float* __restrict__ Wv, const float* __restrict__ Wg,
                                 const float* __restrict__ Wt,
                                 __bf16* __restrict__ WvT, __bf16* __restrict__ WgT,
                                 __bf16* __restrict__ WtT) {
    __shared__ float t[32][33];
    int b = blockIdx.x;
    const float* src; __bf16* dst; int R, C, tile;
    if (b < 1024)      { src = Wv; dst = WvT; R = 1024; C = 1024; tile = b; }
    else if (b < 1536) { src = Wg; dst = WgT; R = 1024; C = 512;  tile = b - 1024; }
    else               { src = Wt; dst = WtT; R = 1024; C = 768;  tile = b - 1536; }
    int tx_n = C >> 5;
    int c0 = (tile % tx_n) << 5, r0 = (tile / tx_n) << 5;
    int tx = threadIdx.x, ty = threadIdx.y;  // 32 x 8
    #pragma unroll
    for (int i = 0; i < 32; i += 8)
        t[ty + i][tx] = src[(long)(r0 + ty + i) * C + c0 + tx];
    __syncthreads();
    #pragma unroll
    for (int i = 0; i < 32; i += 8)
        dst[(long)(c0 + ty + i) * R + r0 + tx] = (__bf16)t[tx][ty + i];
}

// ---------------- bias helpers ----------------
__global__ void k_bias_att(const float* __restrict__ Wo, const float* __restrict__ bv,
                           const float* __restrict__ bo, float* __restrict__ b_att) {
    int i = blockIdx.x;
    float s = 0.f;
    for (int k = threadIdx.x; k < 1024; k += 256) s += Wo[i * 1024 + k] * bv[k];
    __shared__ float red[256];
    red[threadIdx.x] = s;
    __syncthreads();
    for (int off = 128; off > 0; off >>= 1) {
        if (threadIdx.x < off) red[threadIdx.x] += red[threadIdx.x + off];
        __syncthreads();
    }
    if (threadIdx.x == 0) b_att[i] = red[0] + bo[i];
}

__global__ void k_bias_z2(const float* __restrict__ W1, const float* __restrict__ b_att,
                          const float* __restrict__ b1,
                          const __bf16* __restrict__ P, const __bf16* __restrict__ Q,
                          const float* __restrict__ bt, const float* __restrict__ bg,
                          const float* __restrict__ b2,
                          float* __restrict__ bz2, float* __restrict__ b_out) {
    int i = blockIdx.x;
    float s = 0.f;
    for (int k = threadIdx.x; k < 1024; k += 256) {
        s += (W1[(long)i * 2048 + k] + W1[(long)i * 2048 + 1024 + k]) * b_att[k];
        s += (float)P[i * 1024 + k] * bt[k];
        s += (float)Q[i * 1024 + k] * bg[k];
    }
    __shared__ float red[256];
    red[threadIdx.x] = s;
    __syncthreads();
    for (int off = 128; off > 0; off >>= 1) {
        if (threadIdx.x < off) red[threadIdx.x] += red[threadIdx.x + off];
        __syncthreads();
    }
    if (threadIdx.x == 0) {
        bz2[i] = red[0] + b1[i];
        b_out[i] = b2[i] + bg[i] + bt[i];
    }
}

// ---------------- small NT GEMM (64x64 tiles, 2-phase, verified) ----------------
template <int BM, int BN>
__global__ __launch_bounds__(256, 2) void k_gemm_nt(
    const __bf16* __restrict__ A, int lda,
    const __bf16* __restrict__ B, int ldb,
    __bf16* __restrict__ C, int ldc,
    int K, int n_tiles) {
    constexpr int BK = 32;
    constexpr int MR = BM / 32, NR = BN / 32;
    __shared__ alignas(16) __bf16 As[2][BM][BK];
    __shared__ alignas(16) __bf16 Bs[2][BN][BK];

    const int tid = threadIdx.x;
    const int lane = tid & 63;
    const int wave = tid >> 6;
    int bid = blockIdx.x;
    const int nwg = gridDim.x;
    if ((nwg & 7) == 0) bid = (bid & 7) * (nwg >> 3) + (bid >> 3);
    const int bn = bid % n_tiles;
    const int bm = bid / n_tiles;
    const int m0 = bm * BM, n0 = bn * BN;

    const int rp_l = tid >> 2;
    const int sp = tid & 3;

    const int wr = (wave >> 1) * (BM / 2);
    const int wc = (wave & 1) * (BN / 2);
    const int fr = lane & 15;
    const int fb = (lane >> 4) << 4;

    f32x4 acc[MR][NR] = {};
    const int nk = K / BK;

    auto stage = [&](int buf, int kt) {
        char* abase = (char*)&As[buf][0][0];
        char* bbase = (char*)&Bs[buf][0][0];
        #pragma unroll
        for (int it = 0; it < BM / 64; ++it) {
            int rp = it * 64 + rp_l;
            int rl = (rp & ~1) | ((rp ^ (rp >> 2)) & 1);
            int sl = sp ^ (rl & 3);
            gload16(A + (long)(m0 + rl) * lda + kt * BK + sl * 8,
                    abase + it * 4096 + tid * 16);
        }
        #pragma unroll
        for (int it = 0; it < BN / 64; ++it) {
            int rp = it * 64 + rp_l;
            int rl = (rp & ~1) | ((rp ^ (rp >> 2)) & 1);
            int sl = sp ^ (rl & 3);
            gload16(B + (long)(n0 + rl) * ldb + kt * BK + sl * 8,
                    bbase + it * 4096 + tid * 16);
        }
    };

    stage(0, 0);
    for (int kt = 0; kt < nk; ++kt) {
        const int buf = kt & 1;
        __syncthreads();
        if (kt + 1 < nk) stage(buf ^ 1, kt + 1);
        const char* abase = (const char*)&As[buf][0][0];
        const char* bbase = (const char*)&Bs[buf][0][0];
        bf16x8 af[MR], bfr[NR];
        #pragma unroll
        for (int m = 0; m < MR; ++m) {
            int r = wr + m * 16 + fr;
            af[m] = *(const bf16x8*)(abase + (((r << 6) + fb) ^ ((r & 7) << 4)));
        }
        #pragma unroll
        for (int n = 0; n < NR; ++n) {
            int r = wc + n * 16 + fr;
            bfr[n] = *(const bf16x8*)(bbase + (((r << 6) + fb) ^ ((r & 7) << 4)));
        }
        #pragma unroll
        for (int m = 0; m < MR; ++m)
            #pragma unroll
            for (int n = 0; n < NR; ++n)
                acc[m][n] = __builtin_amdgcn_mfma_f32_16x16x32_bf16(af[m], bfr[n], acc[m][n], 0, 0, 0);
    }

    const int r0 = (lane >> 4) << 2;
    #pragma unroll
    for (int n = 0; n < NR; ++n) {
        const int gc = n0 + wc + n * 16 + fr;
        #pragma unroll
        for (int m = 0; m < MR; ++m) {
            const long rbase = (long)(m0 + wr + m * 16 + r0);
            #pragma unroll
            for (int r = 0; r < 4; ++r)
                C[(rbase + r) * ldc + gc] = (__bf16)acc[m][n][r];
        }
    }
}

// ------------- 8-phase 256x256 NT GEMM (8 waves, BK=64, counted vmcnt) ----------
// LDS: [parity][k-half][256][32] bf16; half-tile = contiguous 16KB, staged by
// 512 threads x 2 gload16. XOR swizzle pair (r2-verified formulas) on both sides.
// Phases per iteration (K-tiles t=2I,t+1): quadrant (ks, mh); B-frags read at
// mh==0 and reused. Stage map proven write-after-free; vmcnt(4) at P4/P8 only.
// MODE 1: +bias, exact GELU, bf16 out; MODE 2: +bias, fp32 out.
template <int MODE>
__global__ __launch_bounds__(512, 2) void k_gemm8(
    const __bf16* __restrict__ A, int lda,
    const __bf16* __restrict__ B, int ldb,
    void* __restrict__ Cv, int ldc,
    const float* __restrict__ bias,
    int K, int n_tiles) {
    __shared__ __bf16 As[2][2][256][32];
    __shared__ __bf16 Bs[2][2][256][32];

    const int tid = threadIdx.x;
    const int lane = tid & 63;
    const int wave = tid >> 6;
    const int wm = wave >> 2;   // 0..1 -> 128 M-rows
    const int wn = wave & 3;    // 0..3 -> 64 N-cols

    int bid = blockIdx.x;
    const int nwg = gridDim.x;
    if ((nwg & 7) == 0) bid = (bid & 7) * (nwg >> 3) + (bid >> 3);
    const int bn = bid % n_tiles;
    const int bm = bid / n_tiles;
    const int m0 = bm * 256, n0 = bn * 256;

    // staging precompute (inverse swizzle, r2-verified)
    const int rp0 = tid >> 2;                              // 0..127
    const int rl0 = (rp0 & ~1) | ((rp0 ^ (rp0 >> 2)) & 1); // logical row
    const int slo = (tid & 3) ^ (rl0 & 3);                 // logical 16B slot
    const __bf16* Ag = A + (long)(m0 + rl0) * lda + slo * 8;
    const __bf16* Bg = B + (long)(n0 + rl0) * ldb + slo * 8;
    const long lda128 = (long)128 * lda;
    const long ldb128 = (long)128 * ldb;
    const int tid16 = tid * 16;

    const int fr = lane & 15;
    const int gb = (lane >> 4) << 4;

    f32x4 acc[8][4] = {};
    bf16x8 bfr[4];

    const int nk = K >> 6;
    const int NI = nk >> 1;

#define STAGE_A(PAR, KT, KH) { \
        char* l_ = (char*)&As[PAR][KH][0][0] + tid16; \
        const __bf16* g_ = Ag + (long)(KT) * 64 + (KH) * 32; \
        gload16(g_, l_); \
        gload16(g_ + lda128, l_ + 8192); }
#define STAGE_B(PAR, KT, KH) { \
        char* l_ = (char*)&Bs[PAR][KH][0][0] + tid16; \
        const __bf16* g_ = Bg + (long)(KT) * 64 + (KH) * 32; \
        gload16(g_, l_); \
        gload16(g_ + ldb128, l_ + 8192); }
#define VMC4 asm volatile("s_waitcnt vmcnt(4)" ::: "memory")
#define VMC0 asm volatile("s_waitcnt vmcnt(0)" ::: "memory")
#define PHASE(PAR, KS, MH, STAGES, WAITS) { \
        bf16x8 af[4]; \
        if ((MH) == 0) { \
            const char* b_ = (const char*)&Bs[PAR][KS][0][0]; \
            _Pragma("unroll") \
            for (int n_ = 0; n_ < 4; ++n_) { \
                int r_ = wn * 64 + n_ * 16 + fr; \
                bfr[n_] = *(const bf16x8*)(b_ + (((r_ << 6) + gb) ^ ((r_ & 7) << 4))); } } \
        { const char* a_ = (const char*)&As[PAR][KS][0][0]; \
          _Pragma("unroll") \
          for (int m_ = 0; m_ < 4; ++m_) { \
              int r_ = wm * 128 + (MH) * 64 + m_ * 16 + fr; \
              af[m_] = *(const bf16x8*)(a_ + (((r_ << 6) + gb) ^ ((r_ & 7) << 4))); } } \
        STAGES; \
        WAITS; \
        __builtin_amdgcn_s_barrier(); \
        __builtin_amdgcn_s_setprio(1); \
        _Pragma("unroll") \
        for (int m_ = 0; m_ < 4; ++m_) { \
            _Pragma("unroll") \
            for (int n_ = 0; n_ < 4; ++n_) \
                acc[(MH) * 4 + m_][n_] = __builtin_amdgcn_mfma_f32_16x16x32_bf16( \
                    af[m_], bfr[n_], acc[(MH) * 4 + m_][n_], 0, 0, 0); } \
        __builtin_amdgcn_s_setprio(0); \
        __builtin_amdgcn_s_barrier(); }

    // prologue: t0.{B0,A0,B1,A1}, t1.{B0,A0,B1}; then vmcnt(4) -> t0 resident
    STAGE_B(0, 0, 0); STAGE_A(0, 0, 0); STAGE_B(0, 0, 1); STAGE_A(0, 0, 1);
    STAGE_B(1, 1, 0); STAGE_A(1, 1, 0); STAGE_B(1, 1, 1);
    VMC4;
    __builtin_amdgcn_s_barrier();

    for (int I = 0; I < NI; ++I) {
        const int t = 2 * I;
        const bool nl = (I < NI - 1);
        PHASE(0, 0, 0, { STAGE_A(1, t + 1, 1); }, {});
        PHASE(0, 0, 1, { if (nl) STAGE_B(0, t + 2, 0); }, {});
        PHASE(0, 1, 0, { if (nl) STAGE_A(0, t + 2, 0); }, {});
        PHASE(0, 1, 1, { if (nl) STAGE_B(0, t + 2, 1); },
              { if (nl) { VMC4; } else { VMC0; } });
        PHASE(1, 0, 0, { if (nl) STAGE_A(0, t + 2, 1); }, {});
        PHASE(1, 0, 1, { if (nl) STAGE_B(1, t + 3, 0); }, {});
        PHASE(1, 1, 0, { if (nl) STAGE_A(1, t + 3, 0); }, {});
        PHASE(1, 1, 1, { if (nl) STAGE_B(1, t + 3, 1); },
              { if (nl) { VMC4; } });
    }
#undef PHASE
#undef STAGE_A
#undef STAGE_B
#undef VMC4
#undef VMC0

    // epilogue: D row = (lane>>4)*4 + r, col = lane&15 per 16x16 frag
    const int r0q = (lane >> 4) << 2;
    #pragma unroll
    for (int n = 0; n < 4; ++n) {
        const int gc = n0 + wn * 64 + n * 16 + fr;
        const float bval = bias ? bias[gc] : 0.0f;
        #pragma unroll
        for (int mq = 0; mq < 8; ++mq) {
            const long rbase = (long)(m0 + wm * 128 + mq * 16 + r0q);
            #pragma unroll
            for (int r = 0; r < 4; ++r) {
                float v = acc[mq][n][r] + bval;
                const long row = rbase + r;
                if (MODE == 1) {
                    v = 0.5f * v * (1.0f + erff(v * 0.70710678118f));
                    ((__bf16*)Cv)[row * ldc + gc] = (__bf16)v;
                } else {
                    ((float*)Cv)[row * ldc + gc] = v;
                }
            }
        }
    }
}

// ---------------- host ----------------
extern "C" void kernel_launch(void* const* d_in, const int* in_sizes, int n_in,
                              void* d_out, int out_size, void* d_ws, size_t ws_size,
                              hipStream_t stream) {
    constexpr int Bsz = 16384, F = 1024, GD = 512, TD = 768;
    constexpr int XLD = F + GD + TD;  // 2304

    const float* gnn = (const float*)d_in[0];
    const float* tr  = (const float*)d_in[1];
    const float* Wg  = (const float*)d_in[2];
    const float* bg  = (const float*)d_in[3];
    const float* Wt  = (const float*)d_in[4];
    const float* bt  = (const float*)d_in[5];
    const float* Wv  = (const float*)d_in[6];
    const float* bv  = (const float*)d_in[7];
    const float* Wo  = (const float*)d_in[8];
    const float* bo  = (const float*)d_in[9];
    const float* W1  = (const float*)d_in[10];
    const float* b1  = (const float*)d_in[11];
    const float* W2  = (const float*)d_in[12];
    const float* b2  = (const float*)d_in[13];
    float* out = (float*)d_out;

    char* w = (char*)d_ws;
    auto alloc = [&](size_t bytes) {
        char* p = w;
        w += (bytes + 255) & ~(size_t)255;
        return p;
    };
    __bf16* X    = (__bf16*)alloc((size_t)Bsz * XLD * 2);       // [h | gnn | tr]
    __bf16* M1   = (__bf16*)alloc((size_t)F * (GD + TD) * 2);   // [Mg | Mt]
    __bf16* Wp   = (__bf16*)alloc((size_t)F * XLD * 2);         // [W2 | Wg | Wt]
    __bf16* WvT  = (__bf16*)alloc((size_t)F * F * 2);
    __bf16* WgT  = (__bf16*)alloc((size_t)GD * F * 2);
    __bf16* WtT  = (__bf16*)alloc((size_t)TD * F * 2);
    __bf16* Wo_b = (__bf16*)alloc((size_t)F * F * 2);
    __bf16* W1ab = (__bf16*)alloc((size_t)2 * F * F * 2);       // [W1a ; W1b]
    __bf16* AT   = (__bf16*)alloc((size_t)F * F * 2);
    __bf16* PQ   = (__bf16*)alloc((size_t)2 * F * F * 2);       // [P ; Q]
    float* b_att = (float*)alloc(F * 4);
    float* bz2   = (float*)alloc(F * 4);
    float* b_out = (float*)alloc(F * 4);
    if ((size_t)(w - (char*)d_ws) > ws_size) return;

    dim3 b256(256);
    __bf16* P = PQ;
    __bf16* Q = PQ + (size_t)F * F;

    k_prep_convert<<<dim3(12928), b256, 0, stream>>>(gnn, tr, Wo, W1, W2, Wg, Wt,
                                                     X, Wo_b, W1ab, Wp);
    k_prep_transpose<<<dim3(2304), dim3(32, 8), 0, stream>>>(Wv, Wg, Wt, WvT, WgT, WtT);
    k_bias_att<<<dim3(F), b256, 0, stream>>>(Wo, bv, bo, b_att);

    // weight-composition GEMMs
    k_gemm_nt<64, 64><<<dim3((F / 64) * (F / 64)), b256, 0, stream>>>(
        WvT, F, Wo_b, F, AT, F, F, F / 64);
    k_gemm_nt<64, 64><<<dim3((2 * F / 64) * (F / 64)), b256, 0, stream>>>(
        W1ab, F, AT, F, PQ, F, F, F / 64);
    k_gemm_nt<64, 64><<<dim3((F / 64) * (GD / 64)), b256, 0, stream>>>(
        Q, F, WgT, F, M1, GD + TD, F, GD / 64);
    k_gemm_nt<64, 64><<<dim3((F / 64) * (TD / 64)), b256, 0, stream>>>(
        P, F, WtT, F, M1 + GD, GD + TD, F, TD / 64);

    k_bias_z2<<<dim3(F), b256, 0, stream>>>(W1, b_att, b1, P, Q, bt, bg, b2, bz2, b_out);

    // pass 1: h = gelu([gnn|tr] @ M1^T + bz2) -> X[:, 0:1024] (bf16)   K=1280
    k_gemm8<1><<<dim3((Bsz / 256) * (F / 256)), dim3(512), 0, stream>>>(
        X + F, XLD, M1, GD + TD, X, XLD, bz2, GD + TD, F / 256);

    // pass 2: out = [h|gnn|tr] @ [W2|Wg|Wt]^T + b_out (fp32)           K=2304
    k_gemm8<2><<<dim3((Bsz / 256) * (F / 256)), dim3(512), 0, stream>>>(
        X, XLD, Wp, XLD, out, F, b_out, XLD, F / 256);
}